// Round 1
// baseline (108.849 us; speedup 1.0000x reference)
//
#include <hip/hip_runtime.h>
#include <math.h>

// OnlinePGHI: M2 == 1 makes the 2-D heap flood-fill collapse to independent
// 1-D segments. phase[i] = cum[i] - cum[seed(i)] within each alive segment,
// where cum is the trapezoid integral of the time-direction phase gradient
// and seed is the first-max of mag within the segment. mag_buffer (fgradw)
// is dead code because North/South neighbors are never valid.

#define NBINS 511   // N_FFT/2 - 1
#define NX    513   // N_FFT/2 + 1
#define ABSTOL 1e-10f

__global__ __launch_bounds__(512) void OnlinePGHI_66073776882009_kernel(
    const float* __restrict__ x, float* __restrict__ out) {
  __shared__ float xlog[NX];
  __shared__ float tg[NBINS];
  __shared__ float cum[512];
  __shared__ int   seedOf[NBINS];

  const int tid = threadIdx.x;

  // ---- constants (compile-time, double precision) ----
  constexpr double kPi    = 3.14159265358979323846;
  constexpr double kLn001 = -4.60517018598809136804;            // ln(0.01)
  constexpr double kGamma = 2.0 * kPi * (-(1024.0 * 1024.0) / (8.0 * kLn001));
  constexpr double kFmul  = kGamma / (2.0 * 256.0 * 1024.0);    // GAMMA/(2*HOP*NFFT)
  constexpr double kInv4F = 1.0 / (4.0 * kFmul);
  const float inv4f = (float)kInv4F;
  const float wstep = (float)(kPi / 2.0);                       // 2*pi*HOP/NFFT

  // ---- x_log ----
  for (int i = tid; i < NX; i += 512) xlog[i] = logf(x[i]);
  __syncthreads();

  // ---- tgradw[i], i = 0..510 (bin k = i+1) ----
  if (tid < NBINS)
    tg[tid] = inv4f * (xlog[tid + 2] - xlog[tid]) + wstep * (float)(tid + 1);
  __syncthreads();

  // ---- trapezoid steps -> inclusive prefix sum (Hillis-Steele, 9 passes) ----
  if (tid == 0)            cum[0]   = 0.0f;
  else if (tid < NBINS)    cum[tid] = 0.5f * (tg[tid - 1] + tg[tid]);
  else                     cum[tid] = 0.0f;
  __syncthreads();
  for (int off = 1; off < 512; off <<= 1) {
    float v = cum[tid];
    float a = (tid >= off) ? cum[tid - off] : 0.0f;
    __syncthreads();
    cum[tid] = v + a;
    __syncthreads();
  }

  // ---- per-segment first-occurrence argmax of mag (serial, 511 iters) ----
  if (tid == 0) {
    int i = 0;
    while (i < NBINS) {
      float m0 = xlog[i + 1];
      if (!(m0 > ABSTOL)) { seedOf[i] = -1; ++i; continue; }
      int j = i, best = i;
      float bm = m0;
      while (j + 1 < NBINS) {
        float m = xlog[j + 2];
        if (!(m > ABSTOL)) break;
        ++j;
        if (m > bm) { bm = m; best = j; }
      }
      for (int k = i; k <= j; ++k) seedOf[k] = best;
      i = j + 1;
    }
  }
  __syncthreads();

  // ---- phase out ----
  if (tid < NBINS) {
    int s = seedOf[tid];
    out[tid] = (s >= 0) ? (cum[tid] - cum[s]) : 0.0f;
  }
}

extern "C" void kernel_launch(void* const* d_in, const int* in_sizes, int n_in,
                              void* d_out, int out_size, void* d_ws, size_t ws_size,
                              hipStream_t stream) {
  const float* x = (const float*)d_in[0];
  // d_in[1] (mag_buffer) is provably unused: fgradw only feeds N/S updates,
  // which are invalid for M2 == 1.
  float* out = (float*)d_out;
  OnlinePGHI_66073776882009_kernel<<<1, 512, 0, stream>>>(x, out);
}

// Round 2
// 58.396 us; speedup vs baseline: 1.8640x; 1.8640x over previous
//
#include <hip/hip_runtime.h>
#include <math.h>

// OnlinePGHI, fully parallel form.
// M2 == 1 collapses the 2-D heap flood-fill to independent 1-D segments:
//   phase[i] = cum[i] - cum[seed(seg(i))]   for alive bins (log(x[i+1]) > ABSTOL)
//   phase[i] = 0                            for dead bins
// where cum = inclusive trapezoid integral of tgradw and seed = first-occurrence
// argmax of mag within the segment. mag_buffer (fgradw) is dead code (N/S
// neighbors never valid for M2==1).
//
// Round-1 lesson: the serial thread-0 seed pass cost ~40 us of dependent-LDS
// latency. This version finds seeds in parallel: segment ids via a shfl-based
// prefix sum of start flags, per-segment argmax via LDS atomicMax on a packed
// (value_bits, NBINS-i) 64-bit key (first-occurrence-of-max tie-break).

#define NBINS 511   // N_FFT/2 - 1
#define NX    513   // N_FFT/2 + 1
#define ABSTOL 1e-10f
#define NTH   512

__global__ __launch_bounds__(NTH) void OnlinePGHI_66073776882009_kernel(
    const float* __restrict__ x, float* __restrict__ out) {
  __shared__ float xlog[NX];
  __shared__ float cum[NTH];
  __shared__ float wsumF[8];
  __shared__ int   wsumI[8];
  __shared__ unsigned long long segKey[256];  // max 256 segments over 511 bins

  const int tid  = threadIdx.x;
  const int lane = tid & 63;
  const int wave = tid >> 6;

  // ---- constants (compile-time, double precision) ----
  constexpr double kPi    = 3.14159265358979323846;
  constexpr double kLn001 = -4.60517018598809136804;            // ln(0.01)
  constexpr double kGamma = 2.0 * kPi * (-(1024.0 * 1024.0) / (8.0 * kLn001));
  constexpr double kFmul  = kGamma / (2.0 * 256.0 * 1024.0);    // GAMMA/(2*HOP*NFFT)
  const float inv4f = (float)(1.0 / (4.0 * kFmul));
  const float wstep = (float)(kPi / 2.0);                       // 2*pi*HOP/NFFT

  // ---- x_log (513 elements: thread 0 also loads the tail) ----
  xlog[tid] = logf(x[tid]);
  if (tid == 0) xlog[NX - 1] = logf(x[NX - 1]);
  if (tid < 256) segKey[tid] = 0ULL;
  __syncthreads();

  // ---- per-bin values: trapezoid step, alive flag, segment-start flag ----
  float stepv = 0.0f;
  int   flag  = 0;
  bool  alive = false;
  float m     = 0.0f;
  if (tid < NBINS) {
    m     = xlog[tid + 1];                       // mag[i] = log(x[i+1])
    alive = m > ABSTOL;
    bool alivePrev = (tid > 0) && (xlog[tid] > ABSTOL);
    flag = (alive && !alivePrev) ? 1 : 0;
    if (tid > 0) {
      // tg(i) = inv4f*(xlog[i+2]-xlog[i]) + wstep*(i+1); recompute both, no LDS pass
      float tgi  = inv4f * (xlog[tid + 2] - xlog[tid])     + wstep * (float)(tid + 1);
      float tgim = inv4f * (xlog[tid + 1] - xlog[tid - 1]) + wstep * (float)(tid);
      stepv = 0.5f * (tgim + tgi);
    }
  }

  // ---- fused wave-inclusive scans (float steps + int flags), 6 shfl steps ----
  float sF = stepv;
  int   sI = flag;
  #pragma unroll
  for (int off = 1; off < 64; off <<= 1) {
    float oF = __shfl_up(sF, off, 64);
    int   oI = __shfl_up(sI, off, 64);
    if (lane >= off) { sF += oF; sI += oI; }
  }
  if (lane == 63) { wsumF[wave] = sF; wsumI[wave] = sI; }
  __syncthreads();
  #pragma unroll
  for (int w = 0; w < 8; ++w) {
    if (w < wave) { sF += wsumF[w]; sI += wsumI[w]; }
  }

  // ---- publish cum; per-segment first-max argmax via packed-key atomicMax ----
  cum[tid] = sF;
  const int segid = sI - 1;
  if (alive) {
    // positive float -> bit pattern is order-preserving; low word favors small i
    unsigned long long key =
        ((unsigned long long)__float_as_uint(m) << 32) | (unsigned)(NBINS - tid);
    atomicMax(&segKey[segid], key);
  }
  __syncthreads();

  // ---- phase out ----
  if (tid < NBINS) {
    float r = 0.0f;
    if (alive) {
      int s = NBINS - (int)(segKey[segid] & 0xffffffffULL);
      r = cum[tid] - cum[s];
    }
    out[tid] = r;
  }
}

extern "C" void kernel_launch(void* const* d_in, const int* in_sizes, int n_in,
                              void* d_out, int out_size, void* d_ws, size_t ws_size,
                              hipStream_t stream) {
  const float* x = (const float*)d_in[0];
  // d_in[1] (mag_buffer) is provably unused: fgradw only feeds N/S updates,
  // which are invalid for M2 == 1.
  float* out = (float*)d_out;
  OnlinePGHI_66073776882009_kernel<<<1, NTH, 0, stream>>>(x, out);
}

// Round 3
// 58.017 us; speedup vs baseline: 1.8762x; 1.0065x over previous
//
#include <hip/hip_runtime.h>
#include <math.h>

// OnlinePGHI, single-wave latency-optimized form.
// M2 == 1 collapses the 2-D heap flood-fill to independent 1-D segments:
//   phase[i] = cum[i] - cum[seed(seg(i))]  for alive bins (log(x[i+1]) > ABSTOL)
//   phase[i] = 0                           for dead bins
// cum = inclusive trapezoid integral of tgradw; seed = first-occurrence argmax
// of mag within the segment. mag_buffer (fgradw) is dead code (N/S neighbors
// never valid for M2==1).
//
// One wave (64 lanes x 8 bins each): no LDS staging of xlog (each lane
// recomputes its 11 overlapping logs), fused float+int shfl scan, one barrier.

#define NBINS 511   // N_FFT/2 - 1
#define NX    513   // N_FFT/2 + 1
#define ABSTOL 1e-10f

__global__ __launch_bounds__(64) void OnlinePGHI_66073776882009_kernel(
    const float* __restrict__ x, float* __restrict__ out) {
  __shared__ float cum[512];
  __shared__ unsigned long long segKey[256];  // max 256 segments over 511 bins

  const int tid  = threadIdx.x;   // 0..63, single wave
  const int base = tid << 3;      // 8 bins per lane

  // ---- constants (compile-time, double precision) ----
  constexpr double kPi    = 3.14159265358979323846;
  constexpr double kLn001 = -4.60517018598809136804;            // ln(0.01)
  constexpr double kGamma = 2.0 * kPi * (-(1024.0 * 1024.0) / (8.0 * kLn001));
  constexpr double kFmul  = kGamma / (2.0 * 256.0 * 1024.0);    // GAMMA/(2*HOP*NFFT)
  const float inv4f = (float)(1.0 / (4.0 * kFmul));
  const float wstep = (float)(kPi / 2.0);                       // 2*pi*HOP/NFFT

  // segment-key init (same wave issues these before the atomics below;
  // the barrier later is the only needed sync)
  #pragma unroll
  for (int j = 0; j < 4; ++j) segKey[(tid << 2) + j] = 0ULL;

  // ---- la[j] = log(x[base-1+j]), j = 0..10 (11 overlapping values) ----
  float la[11];
  #pragma unroll
  for (int j = 0; j < 11; ++j) {
    int idx = base - 1 + j;
    la[j] = (idx >= 0 && idx < NX) ? logf(x[idx]) : 0.0f;  // OOB values unused
  }

  // ---- per-bin step / alive / seg-start flag + local inclusive prefix ----
  float cumLoc[8]; int segLoc[8]; bool aliveK[8]; float magK[8];
  float cf = 0.0f; int ci = 0;
  #pragma unroll
  for (int k = 0; k < 8; ++k) {
    const int i = base + k;
    const float mk = la[k + 2];                       // xlog[i+1]
    const bool av = (i < NBINS) && (mk > ABSTOL);
    const bool avPrev = (i > 0) && (la[k + 1] > ABSTOL);
    const int fl = (av && !avPrev) ? 1 : 0;
    float st = 0.0f;
    if (i > 0 && i < NBINS) {
      float tgi  = inv4f * (la[k + 3] - la[k + 1]) + wstep * (float)(i + 1);
      float tgim = inv4f * (la[k + 2] - la[k])     + wstep * (float)(i);
      st = 0.5f * (tgi + tgim);
    }
    cf += st; ci += fl;
    cumLoc[k] = cf; segLoc[k] = ci; aliveK[k] = av; magK[k] = mk;
  }

  // ---- fused wave scan of per-lane totals -> exclusive offsets ----
  float incF = cf; int incI = ci;
  #pragma unroll
  for (int off = 1; off < 64; off <<= 1) {
    float oF = __shfl_up(incF, off, 64);
    int   oI = __shfl_up(incI, off, 64);
    if (tid >= off) { incF += oF; incI += oI; }
  }
  const float exF = incF - cf;
  const int   exI = incI - ci;

  // ---- publish cum, per-segment first-max argmax via packed-key atomicMax ----
  float cumK[8]; int segidK[8];
  #pragma unroll
  for (int k = 0; k < 8; ++k) {
    const int i = base + k;
    const float cv = exF + cumLoc[k];
    cumK[k] = cv;
    cum[i] = cv;
    const int segid = exI + segLoc[k] - 1;
    segidK[k] = segid;
    if (aliveK[k]) {
      // positive float -> bit pattern order-preserving; low word favors small i
      unsigned long long key =
          ((unsigned long long)__float_as_uint(magK[k]) << 32) |
          (unsigned)(NBINS - i);
      atomicMax(&segKey[segid], key);
    }
  }
  __syncthreads();

  // ---- phase out (two float4 stores per lane; lane 63 handles the 7-tail) ----
  float r[8];
  #pragma unroll
  for (int k = 0; k < 8; ++k) {
    const int i = base + k;
    float v = 0.0f;
    if (i < NBINS && aliveK[k]) {
      int s = NBINS - (int)(segKey[segidK[k]] & 0xffffffffULL);
      v = cumK[k] - cum[s];
    }
    r[k] = v;
  }
  if (tid < 63) {
    float4* o4 = reinterpret_cast<float4*>(out + base);
    o4[0] = make_float4(r[0], r[1], r[2], r[3]);
    o4[1] = make_float4(r[4], r[5], r[6], r[7]);
  } else {
    #pragma unroll
    for (int k = 0; k < 7; ++k) out[base + k] = r[k];
  }
}

extern "C" void kernel_launch(void* const* d_in, const int* in_sizes, int n_in,
                              void* d_out, int out_size, void* d_ws, size_t ws_size,
                              hipStream_t stream) {
  const float* x = (const float*)d_in[0];
  // d_in[1] (mag_buffer) is provably unused: fgradw only feeds N/S updates,
  // which are invalid for M2 == 1.
  float* out = (float*)d_out;
  OnlinePGHI_66073776882009_kernel<<<1, 64, 0, stream>>>(x, out);
}